// Round 1
// baseline (1134.528 us; speedup 1.0000x reference)
//
#include <hip/hip_runtime.h>
#include <hip/hip_cooperative_groups.h>
#include <cmath>

namespace cg = cooperative_groups;

#define H 1024
#define VOCAB 50257
#define LSPAN 40
#define GRID 1024
#define NTHR 256

__device__ __forceinline__ float wave_reduce(float v) {
    for (int o = 32; o > 0; o >>= 1) v += __shfl_down(v, o, 64);
    return v;
}

// online log-sum-exp merge: (M,S) <- merge((M,S),(m,s))
__device__ __forceinline__ void lsm_merge(float& M, float& S, float m, float s) {
    if (m > M) { S = S * expf(M - m) + s; M = m; }
    else       { S += s * expf(m - M); }
}

// one LSTM cell element: block handles hidden index j, wave g computes gate g
__device__ __forceinline__ void lstm_cell(
    const int j, const int wave, const int lane, const int tid,
    const float* __restrict__ x, const float* __restrict__ hprev,
    const float* __restrict__ cprev,
    const float* __restrict__ w_ih, const float* __restrict__ w_hh,
    const float* __restrict__ b_ih, const float* __restrict__ b_hh,
    float* __restrict__ h_out, float* __restrict__ c_out,
    float* sred) {
    const int row = wave * H + j;
    const float4* __restrict__ wi4 = (const float4*)(w_ih + (size_t)row * H);
    const float4* __restrict__ wh4 = (const float4*)(w_hh + (size_t)row * H);
    const float4* __restrict__ x4 = (const float4*)x;
    const float4* __restrict__ h4 = (const float4*)hprev;
    float acc = 0.f;
    for (int k = lane; k < 256; k += 64) {
        float4 a = wi4[k], b = x4[k];
        acc += a.x * b.x + a.y * b.y + a.z * b.z + a.w * b.w;
        float4 c = wh4[k], d = h4[k];
        acc += c.x * d.x + c.y * d.y + c.z * d.z + c.w * d.w;
    }
    acc = wave_reduce(acc);
    if (lane == 0) sred[wave] = acc + b_ih[row] + b_hh[row];
    __syncthreads();
    if (tid == 0) {
        const float i = sred[0], f = sred[1], gg = sred[2], o = sred[3];
        const float si = 1.f / (1.f + expf(-i));
        const float sf = 1.f / (1.f + expf(-f));
        const float so = 1.f / (1.f + expf(-o));
        const float c2 = sf * cprev[j] + si * tanhf(gg);
        c_out[j] = c2;
        h_out[j] = so * tanhf(c2);
    }
}

// ---------------- single cooperative kernel: whole decoder step ----------------
__global__ __launch_bounds__(NTHR, 4) void mega_k(
    const int* __restrict__ tok, const float* __restrict__ h0,
    const float* __restrict__ c0, const float* __restrict__ enc,
    const float* __restrict__ emb, const float* __restrict__ attn_w,
    const float* __restrict__ attn_b, const float* __restrict__ comb_w,
    const float* __restrict__ comb_b,
    const float* __restrict__ w_ih0, const float* __restrict__ w_hh0,
    const float* __restrict__ b_ih0, const float* __restrict__ b_hh0,
    const float* __restrict__ w_ih1, const float* __restrict__ w_hh1,
    const float* __restrict__ b_ih1, const float* __restrict__ b_hh1,
    const float* __restrict__ out_w, const float* __restrict__ out_b,
    float* __restrict__ out, float* __restrict__ ws) {
    cg::grid_group grid = cg::this_grid();
    const int bid = blockIdx.x, tid = threadIdx.x;
    const int wave = tid >> 6, lane = tid & 63;

    float* ws_xin   = ws;           // [0, 3072): [embedded ; attn_applied]
    float* ws_x     = ws + 3072;    // [3072, 4096): comb output
    float* ws_lg    = ws + 4096;    // 40 attn logits
    float* ws_stats = ws + 4224;    // 2 * GRID (per-block LSE stats)

    float* out_logp  = out;
    float* out_h     = out + VOCAB;
    float* out_c     = out + VOCAB + 2 * H;
    float* out_attnw = out + VOCAB + 4 * H;

    __shared__ float4 sh4[256];
    __shared__ float sA[256];
    __shared__ float sB[256];
    __shared__ float slg[LSPAN];

    // ---- P1: attention logits (blocks 0..39); block 0 copies emb row ----
    if (bid < LSPAN) {
        const float* __restrict__ er = emb + (size_t)tok[0] * H;
        const float4* __restrict__ w4 = (const float4*)(attn_w + (size_t)bid * 3 * H);
        const float4* __restrict__ e4 = (const float4*)er;
        const float4* __restrict__ h4 = (const float4*)h0;
        float acc = 0.f;
        for (int k = tid; k < 768; k += NTHR) {
            float4 w = w4[k];
            float4 x = (k < 256) ? e4[k] : h4[k - 256];
            acc += w.x * x.x + w.y * x.y + w.z * x.z + w.w * x.w;
        }
        if (bid == 0) ((float4*)ws_xin)[tid] = e4[tid];
        float s = wave_reduce(acc);
        if (lane == 0) sA[wave] = s;
        __syncthreads();
        if (tid == 0) ws_lg[bid] = sA[0] + sA[1] + sA[2] + sA[3] + attn_b[bid];
    }
    grid.sync();

    // ---- P2: softmax(40) + attn_applied (blocks 0..7) ----
    if (bid < 8) {
        if (tid < LSPAN) slg[tid] = ws_lg[tid];
        __syncthreads();
        float m = -1e30f;
        for (int l = 0; l < LSPAN; ++l) m = fmaxf(m, slg[l]);
        float denom = 0.f;
        for (int l = 0; l < LSPAN; ++l) denom += expf(slg[l] - m);
        const int j = bid * NTHR + tid;
        float acc = 0.f;
        for (int l = 0; l < LSPAN; ++l) acc += expf(slg[l] - m) * enc[l * 2 * H + j];
        ws_xin[H + j] = acc / denom;
        if (bid == 0 && tid < LSPAN) out_attnw[tid] = expf(slg[tid] - m) / denom;
    }
    grid.sync();

    // ---- P3: comb GEMV + relu (blocks 0..255, one wave per row) ----
    if (bid < 256) {
        const int r = bid * 4 + wave;
        const float4* __restrict__ w4 = (const float4*)(comb_w + (size_t)r * 3 * H);
        const float4* __restrict__ x4 = (const float4*)ws_xin;
        float acc = 0.f;
        for (int k = lane; k < 768; k += 64) {
            float4 a = w4[k], b = x4[k];
            acc += a.x * b.x + a.y * b.y + a.z * b.z + a.w * b.w;
        }
        acc = wave_reduce(acc);
        if (lane == 0) ws_x[r] = fmaxf(acc + comb_b[r], 0.f);
    }
    grid.sync();

    // ---- P4: LSTM layer 0 (block = hidden index j) ----
    lstm_cell(bid, wave, lane, tid, ws_x, h0, c0, w_ih0, w_hh0, b_ih0, b_hh0,
              out_h, out_c, sA);
    grid.sync();

    // ---- P5: LSTM layer 1 ----
    lstm_cell(bid, wave, lane, tid, out_h, h0 + H, c0 + H, w_ih1, w_hh1, b_ih1,
              b_hh1, out_h + H, out_c + H, sA);
    grid.sync();

    // ---- P6: vocab GEMV, one row per wave, grid-strided; per-block LSE stats ----
    sh4[tid] = ((const float4*)(out_h + H))[tid];
    __syncthreads();
    float M = -1e30f, S = 0.f;
    for (int v = bid * 4 + wave; v < VOCAB; v += GRID * 4) {
        const float4* __restrict__ w4 = (const float4*)(out_w + (size_t)v * H);
        float acc = 0.f;
        #pragma unroll
        for (int k = lane; k < 256; k += 64) {
            float4 a = w4[k];
            float4 b = sh4[k];
            acc += a.x * b.x + a.y * b.y + a.z * b.z + a.w * b.w;
        }
        acc = wave_reduce(acc);
        if (lane == 0) {
            const float val = acc + out_b[v];
            out_logp[v] = val;
            lsm_merge(M, S, val, 1.f);
        }
    }
    if (lane == 0) { sA[wave] = M; sB[wave] = S; }
    __syncthreads();
    if (tid == 0) {
        float Mb = sA[0], Sb = sB[0];
        for (int w = 1; w < 4; ++w) lsm_merge(Mb, Sb, sA[w], sB[w]);
        ws_stats[2 * bid] = Mb;
        ws_stats[2 * bid + 1] = Sb;
    }
    grid.sync();

    // ---- P7+P8 fused: every block reduces stats -> logZ, then subtracts slice ----
    float M2 = -1e30f, S2 = 0.f;
    for (int b = tid; b < GRID; b += NTHR)
        lsm_merge(M2, S2, ws_stats[2 * b], ws_stats[2 * b + 1]);
    sA[tid] = M2;
    sB[tid] = S2;
    __syncthreads();
    for (int stride = 128; stride > 0; stride >>= 1) {
        if (tid < stride) {
            const float m1 = sA[tid], s1 = sB[tid];
            const float m2 = sA[tid + stride], s2 = sB[tid + stride];
            const float mm = fmaxf(m1, m2);
            sA[tid] = mm;
            sB[tid] = s1 * expf(m1 - mm) + s2 * expf(m2 - mm);
        }
        __syncthreads();
    }
    const float logZ = sA[0] + logf(sB[0]);
    for (int v = bid * NTHR + tid; v < VOCAB; v += GRID * NTHR)
        out_logp[v] -= logZ;
}

// ======================= fallback: previous verified 8-kernel path =======================

__global__ void attn_logits_k(const int* __restrict__ tok,
                              const float* __restrict__ h0,
                              const float* __restrict__ emb,
                              const float* __restrict__ attn_w,
                              const float* __restrict__ attn_b,
                              float* __restrict__ ws_logits,
                              float* __restrict__ ws_xin) {
    const int l = blockIdx.x;
    const int t = threadIdx.x;
    const float* __restrict__ er = emb + (size_t)tok[0] * H;
    const float4* __restrict__ w4 = (const float4*)(attn_w + (size_t)l * 3 * H);
    const float4* __restrict__ e4 = (const float4*)er;
    const float4* __restrict__ h4 = (const float4*)h0;
    float acc = 0.f;
    for (int k = t; k < 768; k += 256) {
        float4 w = w4[k];
        float4 x = (k < 256) ? e4[k] : h4[k - 256];
        acc += w.x * x.x + w.y * x.y + w.z * x.z + w.w * x.w;
    }
    if (l == 0 && t < 256) ((float4*)ws_xin)[t] = e4[t];
    __shared__ float lds[4];
    float s = wave_reduce(acc);
    const int wave = t >> 6, lane = t & 63;
    if (lane == 0) lds[wave] = s;
    __syncthreads();
    if (t == 0) ws_logits[l] = lds[0] + lds[1] + lds[2] + lds[3] + attn_b[l];
}

__global__ void attn_apply_k(const float* __restrict__ ws_logits,
                             const float* __restrict__ enc,
                             float* __restrict__ ws_xin,
                             float* __restrict__ out_attnw) {
    __shared__ float lg[LSPAN];
    const int t = threadIdx.x;
    if (t < LSPAN) lg[t] = ws_logits[t];
    __syncthreads();
    float m = -1e30f;
    for (int l = 0; l < LSPAN; ++l) m = fmaxf(m, lg[l]);
    float denom = 0.f;
    for (int l = 0; l < LSPAN; ++l) denom += expf(lg[l] - m);
    const int j = blockIdx.x * 256 + t;
    float acc = 0.f;
    for (int l = 0; l < LSPAN; ++l) acc += expf(lg[l] - m) * enc[l * 2 * H + j];
    ws_xin[H + j] = acc / denom;
    if (blockIdx.x == 0 && t < LSPAN) out_attnw[t] = expf(lg[t] - m) / denom;
}

__global__ void comb_k(const float* __restrict__ ws_xin,
                       const float* __restrict__ comb_w,
                       const float* __restrict__ comb_b,
                       float* __restrict__ ws_x) {
    const int wave = threadIdx.x >> 6, lane = threadIdx.x & 63;
    const int r = blockIdx.x * 4 + wave;
    const float4* __restrict__ w4 = (const float4*)(comb_w + (size_t)r * 3 * H);
    const float4* __restrict__ x4 = (const float4*)ws_xin;
    float acc = 0.f;
    for (int k = lane; k < 768; k += 64) {
        float4 a = w4[k], b = x4[k];
        acc += a.x * b.x + a.y * b.y + a.z * b.z + a.w * b.w;
    }
    acc = wave_reduce(acc);
    if (lane == 0) ws_x[r] = fmaxf(acc + comb_b[r], 0.f);
}

__global__ void lstm_k(const float* __restrict__ x,
                       const float* __restrict__ hprev,
                       const float* __restrict__ cprev,
                       const float* __restrict__ w_ih,
                       const float* __restrict__ w_hh,
                       const float* __restrict__ b_ih,
                       const float* __restrict__ b_hh,
                       float* __restrict__ h_out,
                       float* __restrict__ c_out) {
    const int wave = threadIdx.x >> 6, lane = threadIdx.x & 63;
    __shared__ float g[4];
    lstm_cell(blockIdx.x, wave, lane, threadIdx.x, x, hprev, cprev, w_ih, w_hh,
              b_ih, b_hh, h_out, c_out, g);
}

__global__ void out_gemv_k(const float* __restrict__ hvec,
                           const float* __restrict__ out_w,
                           const float* __restrict__ out_b,
                           float* __restrict__ logits,
                           float* __restrict__ stats) {
    __shared__ float4 h4s[256];
    const int t = threadIdx.x;
    h4s[t] = ((const float4*)hvec)[t];
    __syncthreads();
    const int wave = t >> 6, lane = t & 63;
    const int v = blockIdx.x * 4 + wave;
    float val = -1e30f;
    if (v < VOCAB) {
        const float4* __restrict__ w4 = (const float4*)(out_w + (size_t)v * H);
        float acc = 0.f;
        for (int k = lane; k < 256; k += 64) {
            float4 a = w4[k];
            float4 b = h4s[k];
            acc += a.x * b.x + a.y * b.y + a.z * b.z + a.w * b.w;
        }
        acc = wave_reduce(acc);
        val = acc + out_b[v];
    }
    __shared__ float g[4];
    if (lane == 0) {
        g[wave] = val;
        if (v < VOCAB) logits[v] = val;
    }
    __syncthreads();
    if (t == 0) {
        float m = fmaxf(fmaxf(g[0], g[1]), fmaxf(g[2], g[3]));
        float s = 0.f;
        for (int w = 0; w < 4; ++w)
            if (g[w] > -1e29f) s += expf(g[w] - m);
        stats[2 * blockIdx.x] = m;
        stats[2 * blockIdx.x + 1] = s;
    }
}

__global__ void logz_k(const float* __restrict__ stats, int nblocks,
                       float* __restrict__ logz) {
    const int t = threadIdx.x;
    float M = -1e30f, S = 0.f;
    for (int b = t; b < nblocks; b += 256) {
        const float m = stats[2 * b], s = stats[2 * b + 1];
        if (m > M) { S = S * expf(M - m) + s; M = m; }
        else       { S += s * expf(m - M); }
    }
    __shared__ float Ms[256], Ss[256];
    Ms[t] = M; Ss[t] = S;
    __syncthreads();
    for (int stride = 128; stride > 0; stride >>= 1) {
        if (t < stride) {
            const float m1 = Ms[t], s1 = Ss[t];
            const float m2 = Ms[t + stride], s2 = Ss[t + stride];
            const float mm = fmaxf(m1, m2);
            Ms[t] = mm;
            Ss[t] = s1 * expf(m1 - mm) + s2 * expf(m2 - mm);
        }
        __syncthreads();
    }
    if (t == 0) logz[0] = Ms[0] + logf(Ss[0]);
}

__global__ void finalize_k(float* __restrict__ logits,
                           const float* __restrict__ logz) {
    const int v = blockIdx.x * 256 + threadIdx.x;
    if (v < VOCAB) logits[v] -= logz[0];
}

extern "C" void kernel_launch(void* const* d_in, const int* in_sizes, int n_in,
                              void* d_out, int out_size, void* d_ws, size_t ws_size,
                              hipStream_t stream) {
    const int*   tok    = (const int*)d_in[0];
    const float* h0     = (const float*)d_in[1];
    const float* c0     = (const float*)d_in[2];
    const float* enc    = (const float*)d_in[3];
    const float* emb    = (const float*)d_in[4];
    const float* attn_w = (const float*)d_in[5];
    const float* attn_b = (const float*)d_in[6];
    const float* comb_w = (const float*)d_in[7];
    const float* comb_b = (const float*)d_in[8];
    const float* w_ih0  = (const float*)d_in[9];
    const float* w_hh0  = (const float*)d_in[10];
    const float* b_ih0  = (const float*)d_in[11];
    const float* b_hh0  = (const float*)d_in[12];
    const float* w_ih1  = (const float*)d_in[13];
    const float* w_hh1  = (const float*)d_in[14];
    const float* b_ih1  = (const float*)d_in[15];
    const float* b_hh1  = (const float*)d_in[16];
    const float* out_w  = (const float*)d_in[17];
    const float* out_b  = (const float*)d_in[18];

    float* out = (float*)d_out;
    float* ws  = (float*)d_ws;

    // --- preferred path: single cooperative kernel ---
    void* params[] = {
        (void*)&tok, (void*)&h0, (void*)&c0, (void*)&enc, (void*)&emb,
        (void*)&attn_w, (void*)&attn_b, (void*)&comb_w, (void*)&comb_b,
        (void*)&w_ih0, (void*)&w_hh0, (void*)&b_ih0, (void*)&b_hh0,
        (void*)&w_ih1, (void*)&w_hh1, (void*)&b_ih1, (void*)&b_hh1,
        (void*)&out_w, (void*)&out_b, (void*)&out, (void*)&ws};
    hipError_t err = hipLaunchCooperativeKernel((const void*)mega_k, dim3(GRID),
                                                dim3(NTHR), params, 0, stream);
    if (err == hipSuccess) return;

    // --- fallback: previous verified 8-kernel pipeline ---
    float* ws_xin    = ws;
    float* ws_x      = ws + 3072;
    float* ws_logits = ws + 4096;
    float* ws_logz   = ws + 4160;
    float* ws_stats  = ws + 4224;

    float* out_logp  = out;
    float* out_h     = out + VOCAB;
    float* out_c     = out + VOCAB + 2 * H;
    float* out_attnw = out + VOCAB + 4 * H;

    attn_logits_k<<<LSPAN, 256, 0, stream>>>(tok, h0, emb, attn_w, attn_b,
                                             ws_logits, ws_xin);
    attn_apply_k<<<8, 256, 0, stream>>>(ws_logits, enc, ws_xin, out_attnw);
    comb_k<<<256, 256, 0, stream>>>(ws_xin, comb_w, comb_b, ws_x);
    lstm_k<<<H, 256, 0, stream>>>(ws_x, h0, c0, w_ih0, w_hh0, b_ih0, b_hh0,
                                  out_h, out_c);
    lstm_k<<<H, 256, 0, stream>>>(out_h, h0 + H, c0 + H, w_ih1, w_hh1, b_ih1,
                                  b_hh1, out_h + H, out_c + H);
    const int NB5 = (VOCAB + 3) / 4;
    out_gemv_k<<<NB5, 256, 0, stream>>>(out_h + H, out_w, out_b, out_logp,
                                        ws_stats);
    logz_k<<<1, 256, 0, stream>>>(ws_stats, NB5, ws_logz);
    finalize_k<<<(VOCAB + 255) / 256, 256, 0, stream>>>(out_logp, ws_logz);
}

// Round 2
// 508.149 us; speedup vs baseline: 2.2327x; 2.2327x over previous
//
#include <hip/hip_runtime.h>
#include <cmath>

#define H 1024
#define VOCAB 50257
#define LSPAN 40
#define NB5 3142          // ceil(50257 / 16) vocab-GEMV blocks
#define NBF 50            // ceil(50257 / 1024) finalize blocks

__device__ __forceinline__ float wave_reduce(float v) {
    for (int o = 32; o > 0; o >>= 1) v += __shfl_down(v, o, 64);
    return v;
}

// online log-sum-exp merge: (M,S) <- merge((M,S),(m,s))
__device__ __forceinline__ void lsm_merge(float& M, float& S, float m, float s) {
    if (m > M) { S = S * expf(M - m) + s; M = m; }
    else       { S += s * expf(m - M); }
}

// K1: attention logits (computed redundantly per block) + softmax + attn_applied.
// grid 8 x 256: block b handles output slice j in [b*256, b*256+256).
// block 0 additionally copies the embedding row into ws_xin[0:H] and writes
// the attn_weights output.
__global__ void attn_k(const int* __restrict__ tok,
                       const float* __restrict__ h0,
                       const float* __restrict__ emb,
                       const float* __restrict__ attn_w,
                       const float* __restrict__ attn_b,
                       const float* __restrict__ enc,
                       float* __restrict__ ws_xin,
                       float* __restrict__ out_attnw) {
    const int t = threadIdx.x, bid = blockIdx.x;
    const int wave = t >> 6, lane = t & 63;
    __shared__ float slg[LSPAN];
    const float* __restrict__ er = emb + (size_t)tok[0] * H;
    const float4* __restrict__ e4 = (const float4*)er;
    const float4* __restrict__ h4 = (const float4*)h0;
    // wave w computes logits l = w, w+4, ... (10 per wave)
    for (int l = wave; l < LSPAN; l += 4) {
        const float4* __restrict__ w4 = (const float4*)(attn_w + (size_t)l * 3 * H);
        float acc = 0.f;
        for (int k = lane; k < 768; k += 64) {
            float4 w = w4[k];
            float4 x = (k < 256) ? e4[k] : h4[k - 256];
            acc += w.x * x.x + w.y * x.y + w.z * x.z + w.w * x.w;
        }
        acc = wave_reduce(acc);
        if (lane == 0) slg[l] = acc + attn_b[l];
    }
    if (bid == 0) ((float4*)ws_xin)[t] = e4[t];
    __syncthreads();
    float m = -1e30f;
    for (int l = 0; l < LSPAN; ++l) m = fmaxf(m, slg[l]);
    float denom = 0.f;
    for (int l = 0; l < LSPAN; ++l) denom += expf(slg[l] - m);
    const int j = bid * 256 + t;
    float acc = 0.f;
    for (int l = 0; l < LSPAN; ++l) acc += expf(slg[l] - m) * enc[l * 2 * H + j];
    ws_xin[H + j] = acc / denom;
    if (bid == 0 && t < LSPAN) out_attnw[t] = expf(slg[t] - m) / denom;
}

// K2: comb GEMV 1024 rows x 3072, relu.  One wave per row, 4 rows/block.
__global__ void comb_k(const float* __restrict__ ws_xin,
                       const float* __restrict__ comb_w,
                       const float* __restrict__ comb_b,
                       float* __restrict__ ws_x) {
    const int wave = threadIdx.x >> 6, lane = threadIdx.x & 63;
    const int r = blockIdx.x * 4 + wave;
    const float4* __restrict__ w4 = (const float4*)(comb_w + (size_t)r * 3 * H);
    const float4* __restrict__ x4 = (const float4*)ws_xin;
    float acc = 0.f;
    for (int k = lane; k < 768; k += 64) {
        float4 a = w4[k], b = x4[k];
        acc += a.x * b.x + a.y * b.y + a.z * b.z + a.w * b.w;
    }
    acc = wave_reduce(acc);
    if (lane == 0) ws_x[r] = fmaxf(acc + comb_b[r], 0.f);
}

// K3/K4: one LSTM cell step. One block per hidden element j; wave g computes
// gate g (rows j, 1024+j, 2048+j, 3072+j of w_ih/w_hh).
__global__ void lstm_k(const float* __restrict__ x,
                       const float* __restrict__ hprev,
                       const float* __restrict__ cprev,
                       const float* __restrict__ w_ih,
                       const float* __restrict__ w_hh,
                       const float* __restrict__ b_ih,
                       const float* __restrict__ b_hh,
                       float* __restrict__ h_out,
                       float* __restrict__ c_out) {
    const int wave = threadIdx.x >> 6, lane = threadIdx.x & 63;
    const int j = blockIdx.x;
    const int row = wave * H + j;
    const float4* __restrict__ wi4 = (const float4*)(w_ih + (size_t)row * H);
    const float4* __restrict__ wh4 = (const float4*)(w_hh + (size_t)row * H);
    const float4* __restrict__ x4 = (const float4*)x;
    const float4* __restrict__ h4 = (const float4*)hprev;
    float acc = 0.f;
    for (int k = lane; k < 256; k += 64) {
        float4 a = wi4[k], b = x4[k];
        acc += a.x * b.x + a.y * b.y + a.z * b.z + a.w * b.w;
        float4 c = wh4[k], d = h4[k];
        acc += c.x * d.x + c.y * d.y + c.z * d.z + c.w * d.w;
    }
    acc = wave_reduce(acc);
    __shared__ float g[4];
    if (lane == 0) g[wave] = acc + b_ih[row] + b_hh[row];
    __syncthreads();
    if (threadIdx.x == 0) {
        const float i = g[0], f = g[1], gg = g[2], o = g[3];
        const float si = 1.f / (1.f + expf(-i));
        const float sf = 1.f / (1.f + expf(-f));
        const float so = 1.f / (1.f + expf(-o));
        const float c2 = sf * cprev[j] + si * tanhf(gg);
        const float h2 = so * tanhf(c2);
        c_out[j] = c2;
        h_out[j] = h2;
    }
}

// K5: vocab GEMV (50257 x 1024) + per-block (max, sumexp) stats.
// 1024 threads = 16 waves, one vocab row per wave; h_l1 staged in LDS.
__global__ __launch_bounds__(1024, 2) void out_gemv_k(
    const float* __restrict__ hvec,
    const float* __restrict__ out_w,
    const float* __restrict__ out_b,
    float* __restrict__ logits,
    float* __restrict__ stats) {
    __shared__ float4 sh4[256];
    __shared__ float sM[16], sS[16];
    const int t = threadIdx.x;
    if (t < 256) sh4[t] = ((const float4*)hvec)[t];
    __syncthreads();
    const int wave = t >> 6, lane = t & 63;
    const int v = blockIdx.x * 16 + wave;
    float M = -1e30f, S = 0.f;
    if (v < VOCAB) {
        const float4* __restrict__ w4 = (const float4*)(out_w + (size_t)v * H);
        float acc = 0.f;
        #pragma unroll
        for (int i = 0; i < 4; ++i) {
            const int k = lane + i * 64;
            float4 a = w4[k];
            float4 b = sh4[k];
            acc += a.x * b.x + a.y * b.y + a.z * b.z + a.w * b.w;
        }
        acc = wave_reduce(acc);
        if (lane == 0) {
            const float val = acc + out_b[v];
            logits[v] = val;
            M = val;
            S = 1.f;
        }
    }
    if (lane == 0) { sM[wave] = M; sS[wave] = S; }
    __syncthreads();
    if (t == 0) {
        float Mb = sM[0], Sb = sS[0];
        for (int w = 1; w < 16; ++w) lsm_merge(Mb, Sb, sM[w], sS[w]);
        stats[2 * blockIdx.x] = Mb;
        stats[2 * blockIdx.x + 1] = Sb;
    }
}

// K6: fused logZ + subtract.  Each block redundantly reduces the (small)
// stats array to logZ, then subtracts it from its 1024-wide logits slice.
__global__ __launch_bounds__(1024) void finalize_k(
    const float* __restrict__ stats,
    float* __restrict__ logits) {
    const int t = threadIdx.x;
    const int wave = t >> 6, lane = t & 63;
    float M = -1e30f, S = 0.f;
    for (int b = t; b < NB5; b += 1024)
        lsm_merge(M, S, stats[2 * b], stats[2 * b + 1]);
    // wave-level LSE reduce (lane 0 correct; high lanes hold garbage, unused)
    for (int o = 32; o > 0; o >>= 1) {
        const float m2 = __shfl_down(M, o, 64);
        const float s2 = __shfl_down(S, o, 64);
        lsm_merge(M, S, m2, s2);
    }
    __shared__ float sM[16], sS[16];
    __shared__ float slz;
    if (lane == 0) { sM[wave] = M; sS[wave] = S; }
    __syncthreads();
    if (t == 0) {
        float Mb = sM[0], Sb = sS[0];
        for (int w = 1; w < 16; ++w) lsm_merge(Mb, Sb, sM[w], sS[w]);
        slz = Mb + logf(Sb);
    }
    __syncthreads();
    const float lz = slz;
    const int v = blockIdx.x * 1024 + t;
    if (v < VOCAB) logits[v] -= lz;
}

extern "C" void kernel_launch(void* const* d_in, const int* in_sizes, int n_in,
                              void* d_out, int out_size, void* d_ws, size_t ws_size,
                              hipStream_t stream) {
    const int*   tok    = (const int*)d_in[0];
    const float* h0     = (const float*)d_in[1];
    const float* c0     = (const float*)d_in[2];
    const float* enc    = (const float*)d_in[3];
    const float* emb    = (const float*)d_in[4];
    const float* attn_w = (const float*)d_in[5];
    const float* attn_b = (const float*)d_in[6];
    const float* comb_w = (const float*)d_in[7];
    const float* comb_b = (const float*)d_in[8];
    const float* w_ih0  = (const float*)d_in[9];
    const float* w_hh0  = (const float*)d_in[10];
    const float* b_ih0  = (const float*)d_in[11];
    const float* b_hh0  = (const float*)d_in[12];
    const float* w_ih1  = (const float*)d_in[13];
    const float* w_hh1  = (const float*)d_in[14];
    const float* b_ih1  = (const float*)d_in[15];
    const float* b_hh1  = (const float*)d_in[16];
    const float* out_w  = (const float*)d_in[17];
    const float* out_b  = (const float*)d_in[18];

    float* out = (float*)d_out;
    float* ws  = (float*)d_ws;

    // workspace layout (floats)
    float* ws_xin   = ws;           // [0, 3072)  : [embedded ; attn_applied]
    float* ws_x     = ws + 3072;    // [3072, 4096): comb output (LSTM0 input)
    float* ws_stats = ws + 4224;    // 2 * NB5 floats

    // output layout: log_probs[V], h_new[2*H], c_new[2*H], attn_weights[L]
    float* out_logp  = out;
    float* out_h     = out + VOCAB;
    float* out_c     = out + VOCAB + 2 * H;
    float* out_attnw = out + VOCAB + 4 * H;

    attn_k<<<8, 256, 0, stream>>>(tok, h0, emb, attn_w, attn_b, enc,
                                  ws_xin, out_attnw);
    comb_k<<<256, 256, 0, stream>>>(ws_xin, comb_w, comb_b, ws_x);
    lstm_k<<<H, 256, 0, stream>>>(ws_x, h0, c0, w_ih0, w_hh0, b_ih0, b_hh0,
                                  out_h, out_c);
    lstm_k<<<H, 256, 0, stream>>>(out_h, h0 + H, c0 + H, w_ih1, w_hh1, b_ih1,
                                  b_hh1, out_h + H, out_c + H);
    out_gemv_k<<<NB5, 1024, 0, stream>>>(out_h + H, out_w, out_b, out_logp,
                                         ws_stats);
    finalize_k<<<NBF, 1024, 0, stream>>>(ws_stats, out_logp);
}

// Round 4
// 470.835 us; speedup vs baseline: 2.4096x; 1.0793x over previous
//
#include <hip/hip_runtime.h>
#include <cmath>

#define H 1024
#define VOCAB 50257
#define LSPAN 40
#define NB5 12565         // ceil(50257 / 4) vocab-GEMV blocks
#define NBF 50            // ceil(50257 / 1024) finalize blocks

__device__ __forceinline__ float wave_reduce(float v) {
    for (int o = 32; o > 0; o >>= 1) v += __shfl_down(v, o, 64);
    return v;
}

// online log-sum-exp merge: (M,S) <- merge((M,S),(m,s))
__device__ __forceinline__ void lsm_merge(float& M, float& S, float m, float s) {
    if (m > M) { S = S * expf(M - m) + s; M = m; }
    else       { S += s * expf(m - M); }
}

// K1: attention logits — one block per encoder position l (max parallelism on
// the latency-bound path).  block 0 also copies emb_row into ws_xin[0:1024].
__global__ void attn_logits_k(const int* __restrict__ tok,
                              const float* __restrict__ h0,
                              const float* __restrict__ emb,
                              const float* __restrict__ attn_w,
                              const float* __restrict__ attn_b,
                              float* __restrict__ ws_logits,
                              float* __restrict__ ws_xin) {
    const int l = blockIdx.x;
    const int t = threadIdx.x;
    const float* __restrict__ er = emb + (size_t)tok[0] * H;
    const float4* __restrict__ w4 = (const float4*)(attn_w + (size_t)l * 3 * H);
    const float4* __restrict__ e4 = (const float4*)er;
    const float4* __restrict__ h4 = (const float4*)h0;
    float acc = 0.f;
    for (int k = t; k < 768; k += 256) {
        float4 w = w4[k];
        float4 x = (k < 256) ? e4[k] : h4[k - 256];
        acc += w.x * x.x + w.y * x.y + w.z * x.z + w.w * x.w;
    }
    if (l == 0 && t < 256) ((float4*)ws_xin)[t] = e4[t];
    __shared__ float lds[4];
    float s = wave_reduce(acc);
    const int wave = t >> 6, lane = t & 63;
    if (lane == 0) lds[wave] = s;
    __syncthreads();
    if (t == 0) ws_logits[l] = lds[0] + lds[1] + lds[2] + lds[3] + attn_b[l];
}

// K2: softmax (recomputed redundantly per block, 40 elems) + attn_applied
__global__ void attn_apply_k(const float* __restrict__ ws_logits,
                             const float* __restrict__ enc,
                             float* __restrict__ ws_xin,
                             float* __restrict__ out_attnw) {
    __shared__ float lg[LSPAN];
    const int t = threadIdx.x;
    if (t < LSPAN) lg[t] = ws_logits[t];
    __syncthreads();
    float m = -1e30f;
    for (int l = 0; l < LSPAN; ++l) m = fmaxf(m, lg[l]);
    float denom = 0.f;
    for (int l = 0; l < LSPAN; ++l) denom += expf(lg[l] - m);
    const int j = blockIdx.x * 256 + t;
    float acc = 0.f;
    for (int l = 0; l < LSPAN; ++l) acc += expf(lg[l] - m) * enc[l * 2 * H + j];
    ws_xin[H + j] = acc / denom;
    if (blockIdx.x == 0 && t < LSPAN) out_attnw[t] = expf(lg[t] - m) / denom;
}

// K3: comb GEMV 1024 rows x 3072, relu.  One wave per row, 4 rows/block.
__global__ void comb_k(const float* __restrict__ ws_xin,
                       const float* __restrict__ comb_w,
                       const float* __restrict__ comb_b,
                       float* __restrict__ ws_x) {
    const int wave = threadIdx.x >> 6, lane = threadIdx.x & 63;
    const int r = blockIdx.x * 4 + wave;
    const float4* __restrict__ w4 = (const float4*)(comb_w + (size_t)r * 3 * H);
    const float4* __restrict__ x4 = (const float4*)ws_xin;
    float acc = 0.f;
    for (int k = lane; k < 768; k += 64) {
        float4 a = w4[k], b = x4[k];
        acc += a.x * b.x + a.y * b.y + a.z * b.z + a.w * b.w;
    }
    acc = wave_reduce(acc);
    if (lane == 0) ws_x[r] = fmaxf(acc + comb_b[r], 0.f);
}

// K4/K5: one LSTM cell step. One block per hidden element j; wave g computes
// gate g (rows j, 1024+j, 2048+j, 3072+j of w_ih/w_hh).
__global__ void lstm_k(const float* __restrict__ x,
                       const float* __restrict__ hprev,
                       const float* __restrict__ cprev,
                       const float* __restrict__ w_ih,
                       const float* __restrict__ w_hh,
                       const float* __restrict__ b_ih,
                       const float* __restrict__ b_hh,
                       float* __restrict__ h_out,
                       float* __restrict__ c_out) {
    const int wave = threadIdx.x >> 6, lane = threadIdx.x & 63;
    const int j = blockIdx.x;
    const int row = wave * H + j;
    const float4* __restrict__ wi4 = (const float4*)(w_ih + (size_t)row * H);
    const float4* __restrict__ wh4 = (const float4*)(w_hh + (size_t)row * H);
    const float4* __restrict__ x4 = (const float4*)x;
    const float4* __restrict__ h4 = (const float4*)hprev;
    float acc = 0.f;
    for (int k = lane; k < 256; k += 64) {
        float4 a = wi4[k], b = x4[k];
        acc += a.x * b.x + a.y * b.y + a.z * b.z + a.w * b.w;
        float4 c = wh4[k], d = h4[k];
        acc += c.x * d.x + c.y * d.y + c.z * d.z + c.w * d.w;
    }
    acc = wave_reduce(acc);
    __shared__ float g[4];
    if (lane == 0) g[wave] = acc + b_ih[row] + b_hh[row];
    __syncthreads();
    if (threadIdx.x == 0) {
        const float i = g[0], f = g[1], gg = g[2], o = g[3];
        const float si = 1.f / (1.f + expf(-i));
        const float sf = 1.f / (1.f + expf(-f));
        const float so = 1.f / (1.f + expf(-o));
        const float c2 = sf * cprev[j] + si * tanhf(gg);
        const float h2 = so * tanhf(c2);
        c_out[j] = c2;
        h_out[j] = h2;
    }
}

// K6: vocab GEMV (50257 x 1024) + per-block (max, sumexp) stats.
// One wave per vocab row, 4 rows/block; h_l1 staged in LDS.
__global__ void out_gemv_k(const float* __restrict__ hvec,
                           const float* __restrict__ out_w,
                           const float* __restrict__ out_b,
                           float* __restrict__ logits,
                           float* __restrict__ stats) {
    __shared__ float4 h4s[256];
    const int t = threadIdx.x;
    h4s[t] = ((const float4*)hvec)[t];
    __syncthreads();
    const int wave = t >> 6, lane = t & 63;
    const int v = blockIdx.x * 4 + wave;
    float val = -1e30f;
    if (v < VOCAB) {
        const float4* __restrict__ w4 = (const float4*)(out_w + (size_t)v * H);
        float acc = 0.f;
        for (int k = lane; k < 256; k += 64) {
            float4 a = w4[k];
            float4 b = h4s[k];
            acc += a.x * b.x + a.y * b.y + a.z * b.z + a.w * b.w;
        }
        acc = wave_reduce(acc);
        val = acc + out_b[v];
    }
    __shared__ float g[4];
    if (lane == 0) {
        g[wave] = val;
        if (v < VOCAB) logits[v] = val;
    }
    __syncthreads();
    if (t == 0) {
        float m = fmaxf(fmaxf(g[0], g[1]), fmaxf(g[2], g[3]));
        float s = 0.f;
        for (int w = 0; w < 4; ++w)
            if (g[w] > -1e29f) s += expf(g[w] - m);
        stats[2 * blockIdx.x] = m;
        stats[2 * blockIdx.x + 1] = s;
    }
}

// K7: fused logZ + subtract.  Each block redundantly reduces the stats array
// (12565 pairs ~ 100 KB, L2/L3-served) to logZ, then subtracts it from its
// 1024-wide logits slice.  Replaces the serial 1-block logz_k + finalize_k.
__global__ __launch_bounds__(1024) void finalize_k(
    const float* __restrict__ stats,
    float* __restrict__ logits) {
    const int t = threadIdx.x;
    const int wave = t >> 6, lane = t & 63;
    float M = -1e30f, S = 0.f;
    for (int b = t; b < NB5; b += 1024)
        lsm_merge(M, S, stats[2 * b], stats[2 * b + 1]);
    // wave-level LSE reduce (valid at lane 0)
    for (int o = 32; o > 0; o >>= 1) {
        const float m2 = __shfl_down(M, o, 64);
        const float s2 = __shfl_down(S, o, 64);
        lsm_merge(M, S, m2, s2);
    }
    __shared__ float sM[16], sS[16];
    __shared__ float slz;
    if (lane == 0) { sM[wave] = M; sS[wave] = S; }
    __syncthreads();
    if (t == 0) {
        float Mb = sM[0], Sb = sS[0];
        for (int w = 1; w < 16; ++w) lsm_merge(Mb, Sb, sM[w], sS[w]);
        slz = Mb + logf(Sb);
    }
    __syncthreads();
    const float lz = slz;
    const int v = blockIdx.x * 1024 + t;
    if (v < VOCAB) logits[v] -= lz;
}

extern "C" void kernel_launch(void* const* d_in, const int* in_sizes, int n_in,
                              void* d_out, int out_size, void* d_ws, size_t ws_size,
                              hipStream_t stream) {
    const int*   tok    = (const int*)d_in[0];
    const float* h0     = (const float*)d_in[1];
    const float* c0     = (const float*)d_in[2];
    const float* enc    = (const float*)d_in[3];
    const float* emb    = (const float*)d_in[4];
    const float* attn_w = (const float*)d_in[5];
    const float* attn_b = (const float*)d_in[6];
    const float* comb_w = (const float*)d_in[7];
    const float* comb_b = (const float*)d_in[8];
    const float* w_ih0  = (const float*)d_in[9];
    const float* w_hh0  = (const float*)d_in[10];
    const float* b_ih0  = (const float*)d_in[11];
    const float* b_hh0  = (const float*)d_in[12];
    const float* w_ih1  = (const float*)d_in[13];
    const float* w_hh1  = (const float*)d_in[14];
    const float* b_ih1  = (const float*)d_in[15];
    const float* b_hh1  = (const float*)d_in[16];
    const float* out_w  = (const float*)d_in[17];
    const float* out_b  = (const float*)d_in[18];

    float* out = (float*)d_out;
    float* ws  = (float*)d_ws;

    // workspace layout (floats)
    float* ws_xin    = ws;          // [0, 3072)  : [embedded ; attn_applied]
    float* ws_x      = ws + 3072;   // [3072, 4096): comb output (LSTM0 input)
    float* ws_logits = ws + 4096;   // [4096, 4136): attn logits
    float* ws_stats  = ws + 4224;   // 2 * NB5 floats

    // output layout: log_probs[V], h_new[2*H], c_new[2*H], attn_weights[L]
    float* out_logp  = out;
    float* out_h     = out + VOCAB;
    float* out_c     = out + VOCAB + 2 * H;
    float* out_attnw = out + VOCAB + 4 * H;

    attn_logits_k<<<LSPAN, 256, 0, stream>>>(tok, h0, emb, attn_w, attn_b,
                                             ws_logits, ws_xin);
    attn_apply_k<<<8, 256, 0, stream>>>(ws_logits, enc, ws_xin, out_attnw);
    comb_k<<<256, 256, 0, stream>>>(ws_xin, comb_w, comb_b, ws_x);
    lstm_k<<<H, 256, 0, stream>>>(ws_x, h0, c0, w_ih0, w_hh0, b_ih0, b_hh0,
                                  out_h, out_c);
    lstm_k<<<H, 256, 0, stream>>>(out_h, h0 + H, c0 + H, w_ih1, w_hh1, b_ih1,
                                  b_hh1, out_h + H, out_c + H);
    out_gemv_k<<<NB5, 256, 0, stream>>>(out_h + H, out_w, out_b, out_logp,
                                        ws_stats);
    finalize_k<<<NBF, 1024, 0, stream>>>(ws_stats, out_logp);
}